// Round 8
// baseline (468.086 us; speedup 1.0000x reference)
//
#include <hip/hip_runtime.h>
#include <math.h>

#define NPTS 200000
#define KNBR 16
#define HID 32
#define FINDIM 11

// ---------------------------------------------------------------------------
// Compile-time Threefry-2x32 replication of jax.random.uniform(key(1),(100,3))
// flat elements 0,4,8 -> (u-0.5)*1e-8 noise added to cov columns.
// ---------------------------------------------------------------------------
constexpr unsigned tf_rotl(unsigned x, int r) { return (x << r) | (x >> (32 - r)); }

constexpr unsigned tf_first(unsigned c0, unsigned c1) {
    const unsigned k0 = 0u, k1 = 1u;
    const unsigned k2 = k0 ^ k1 ^ 0x1BD11BDAu;
    unsigned x0 = c0 + k0, x1 = c1 + k1;
    const int rA[4] = {13, 15, 26, 6};
    const int rB[4] = {17, 29, 16, 24};
    for (int i = 0; i < 4; ++i) { x0 += x1; x1 = tf_rotl(x1, rA[i]); x1 ^= x0; }
    x0 += k1; x1 += k2 + 1u;
    for (int i = 0; i < 4; ++i) { x0 += x1; x1 = tf_rotl(x1, rB[i]); x1 ^= x0; }
    x0 += k2; x1 += k0 + 2u;
    for (int i = 0; i < 4; ++i) { x0 += x1; x1 = tf_rotl(x1, rA[i]); x1 ^= x0; }
    x0 += k0; x1 += k1 + 3u;
    for (int i = 0; i < 4; ++i) { x0 += x1; x1 = tf_rotl(x1, rB[i]); x1 ^= x0; }
    x0 += k1; x1 += k2 + 4u;
    for (int i = 0; i < 4; ++i) { x0 += x1; x1 = tf_rotl(x1, rA[i]); x1 ^= x0; }
    x0 += k2; x1 += k0 + 5u;
    return x0;
}

constexpr float tf_noise(unsigned c0, unsigned c1) {
    unsigned bits = tf_first(c0, c1);
    unsigned fb = (bits >> 9) | 0x3f800000u;
    float u = __builtin_bit_cast(float, fb) - 1.0f;
    return (u - 0.5f) * 1e-8f;
}

constexpr float NOISE0 = tf_noise(0u, 150u);
constexpr float NOISE1 = tf_noise(4u, 154u);
constexpr float NOISE2 = tf_noise(8u, 158u);

// ---------------------------------------------------------------------------
// LAPACK-faithful 3x3 symmetric eigensolver, FLOAT32 (ssyevd path).
// LAPACK Fortran objects (ssteqr/slaev2/slartg/slapy2) are compiled at
// baseline ISA (no FMA) -> plain ops, contraction off.
// BLAS calls inside ssytd2/slarf run OpenBLAS arch kernels (FMA) -> fmaf.
// ---------------------------------------------------------------------------

__device__ __forceinline__ float s_sign(float a, float b) {
    float aa = fabsf(a);
    return (b >= 0.0f) ? aa : -aa;
}

__device__ __forceinline__ float slapy2(float x, float y) {
#pragma clang fp contract(off)
    float xa = fabsf(x), ya = fabsf(y);
    float w = fmaxf(xa, ya), z = fminf(xa, ya);
    if (z == 0.0f) return w;
    float t = z / w;
    return w * sqrtf(1.0f + t * t);
}

// LAPACK >= 3.10 slartg (fast path; values O(1))
__device__ __forceinline__ void slartg_new(float f, float g, float &c, float &s, float &r) {
#pragma clang fp contract(off)
    if (g == 0.0f) {
        c = 1.0f; s = 0.0f; r = f;
    } else if (f == 0.0f) {
        c = 0.0f; s = (g >= 0.0f) ? 1.0f : -1.0f; r = fabsf(g);
    } else {
        float d = sqrtf(f * f + g * g);
        c = fabsf(f) / d;
        r = (f >= 0.0f) ? d : -d;
        s = g / r;
    }
}

__device__ void slaev2(float a, float b, float c,
                       float &rt1, float &rt2, float &cs1, float &sn1) {
#pragma clang fp contract(off)
    float sm = a + c;
    float df = a - c;
    float adf = fabsf(df);
    float tb = b + b;
    float ab = fabsf(tb);
    float acmx, acmn;
    if (fabsf(a) > fabsf(c)) { acmx = a; acmn = c; } else { acmx = c; acmn = a; }
    float rt;
    if (adf > ab)      rt = adf * sqrtf(1.0f + (ab / adf) * (ab / adf));
    else if (adf < ab) rt = ab * sqrtf(1.0f + (adf / ab) * (adf / ab));
    else               rt = ab * sqrtf(2.0f);
    int sgn1;
    if (sm < 0.0f) {
        rt1 = 0.5f * (sm - rt);
        sgn1 = -1;
        rt2 = (acmx / rt1) * acmn - (b / rt1) * b;
    } else if (sm > 0.0f) {
        rt1 = 0.5f * (sm + rt);
        sgn1 = 1;
        rt2 = (acmx / rt1) * acmn - (b / rt1) * b;
    } else {
        rt1 = 0.5f * rt;
        rt2 = -0.5f * rt;
        sgn1 = 1;
    }
    int sgn2;
    float cs;
    if (df >= 0.0f) { cs = df + rt; sgn2 = 1; }
    else            { cs = df - rt; sgn2 = -1; }
    float acs = fabsf(cs);
    if (acs > ab) {
        float ct = -tb / cs;
        sn1 = 1.0f / sqrtf(1.0f + ct * ct);
        cs1 = ct * sn1;
    } else {
        if (ab == 0.0f) { cs1 = 1.0f; sn1 = 0.0f; }
        else {
            float tn = -cs / tb;
            cs1 = 1.0f / sqrtf(1.0f + tn * tn);
            sn1 = tn * cs1;
        }
    }
    if (sgn1 == sgn2) {
        float tn = cs1;
        cs1 = -sn1;
        sn1 = tn;
    }
}

// SSYTD2 (lower) n=3: Householder via SLARFG, then SSYMV/SDOT/SAXPY/SSYR2
// with OpenBLAS-arch-kernel FMA semantics (explicit fmaf).
__device__ void ssytrd3(float a00, float a10, float a20,
                        float a11, float a21, float a22,
                        float d[3], float e[2], float &tau, float &v2) {
#pragma clang fp contract(off)
    float alpha = a10;
    float xnorm = fabsf(a20);
    if (xnorm == 0.0f) {
        tau = 0.0f; v2 = 0.0f;
        d[0] = a00; d[1] = a11; d[2] = a22;
        e[0] = alpha; e[1] = a21;
        return;
    }
    float beta = -s_sign(slapy2(alpha, xnorm), alpha);
    tau = (beta - alpha) / beta;
    float sa = 1.0f / (alpha - beta);   // SSCAL: reciprocal then multiply
    v2 = a20 * sa;
    e[0] = beta;
    // SSYMV('L',2,tau,B,u=[1,v2],0): arch kernel, FMA:
    //   x1 = fma(tau, a21*v2, tau*a11); x2 = fma(tau*v2, a22, tau*a21)
    float x1 = fmaf(tau, a21 * v2, tau * a11);
    float x2 = fmaf(tau * v2, a22, tau * a21);
    // SDOT(2,u,x): dot = fma(v2, x2, x1)
    float dot = fmaf(v2, x2, x1);
    // ALPHA = -HALF*TAU*SDOT (Fortran, left-assoc, no FMA)
    float alphaw = (-0.5f * tau) * dot;
    // SAXPY(2, alphaw, u, x): FMA
    float w1 = x1 + alphaw;
    float w2 = fmaf(alphaw, v2, x2);
    // SSYR2('L',2,-1,u,w,B): a_ij = fma(w_i, -u_j, fma(u_i, -w_j, a_ij))
    float b11 = (a11 - w1) - w1;
    float b21 = fmaf(v2, -w1, a21) - w2;
    float b22 = fmaf(w2, -v2, fmaf(v2, -w2, a22));
    d[0] = a00; d[1] = b11; d[2] = b22;
    e[1] = b21;
}

// SSTEQR('I') n=3, mirroring LAPACK control flow, f32 constants, no FMA.
__device__ void ssteqr3(float d[3], float e[2], float z[3][3]) {
#pragma clang fp contract(off)
    const int n = 3;
    const float eps  = 0x1p-24f;
    const float eps2 = 0x1p-48f;
    const float safmin = 0x1p-126f;
    float cwork[2], swork[2];
    const int nmaxit = n * 30;
    int jtot = 0;
    int l1 = 1;

    for (int r = 0; r < 3; r++)
        for (int c = 0; c < 3; c++)
            z[r][c] = (r == c) ? 1.0f : 0.0f;

    while (true) {
        if (l1 > n) break;
        if (l1 > 1) e[l1 - 2] = 0.0f;
        int m = n;
        for (int mm = l1; mm <= n - 1; ++mm) {
            float tst = fabsf(e[mm - 1]);
            if (tst == 0.0f) { m = mm; break; }
            if (tst <= (sqrtf(fabsf(d[mm - 1])) * sqrtf(fabsf(d[mm]))) * eps) {
                e[mm - 1] = 0.0f; m = mm; break;
            }
        }
        int l = l1, lsv = l1, lend = m, lendsv = m;
        l1 = m + 1;
        if (lend == l) continue;

        if (fabsf(d[lend - 1]) < fabsf(d[l - 1])) { lend = lsv; l = lendsv; }

        if (lend > l) {
            // --- QL ---
            bool done = false;
            while (!done) {
                int m2 = lend;
                if (l != lend) {
                    for (int mm = l; mm <= lend - 1; ++mm) {
                        float tst = e[mm - 1] * e[mm - 1];
                        if (tst <= (eps2 * fabsf(d[mm - 1])) * fabsf(d[mm]) + safmin) { m2 = mm; break; }
                    }
                }
                if (m2 < lend) e[m2 - 1] = 0.0f;
                float p = d[l - 1];
                if (m2 == l) {
                    d[l - 1] = p;
                    l = l + 1;
                    if (l > lend) done = true;
                    continue;
                }
                if (m2 == l + 1) {
                    float rt1, rt2, c, s;
                    slaev2(d[l - 1], e[l - 1], d[l], rt1, rt2, c, s);
                    for (int r = 0; r < 3; r++) {
                        float t = z[r][l];
                        z[r][l]     = c * t - s * z[r][l - 1];
                        z[r][l - 1] = s * t + c * z[r][l - 1];
                    }
                    d[l - 1] = rt1; d[l] = rt2; e[l - 1] = 0.0f;
                    l += 2;
                    if (l > lend) done = true;
                    continue;
                }
                if (jtot == nmaxit) { done = true; continue; }
                jtot++;
                float g = (d[l] - p) / (2.0f * e[l - 1]);
                float r = slapy2(g, 1.0f);
                g = d[m2 - 1] - p + (e[l - 1] / (g + s_sign(r, g)));
                float s = 1.0f, c = 1.0f;
                p = 0.0f;
                for (int i = m2 - 1; i >= l; --i) {
                    float f = s * e[i - 1];
                    float b = c * e[i - 1];
                    slartg_new(g, f, c, s, r);
                    if (i != m2 - 1) e[i] = r;
                    g = d[i] - p;
                    r = (d[i - 1] - g) * s + 2.0f * c * b;
                    p = s * r;
                    d[i] = g + p;
                    g = c * r - b;
                    cwork[i - 1] = c;
                    swork[i - 1] = -s;
                }
                for (int j = m2 - 1; j >= l; --j) {
                    float ct = cwork[j - 1], st = swork[j - 1];
                    for (int r2 = 0; r2 < 3; r2++) {
                        float t = z[r2][j];
                        z[r2][j]     = ct * t - st * z[r2][j - 1];
                        z[r2][j - 1] = st * t + ct * z[r2][j - 1];
                    }
                }
                d[l - 1] -= p;
                e[l - 1] = g;
            }
        } else {
            // --- QR ---
            bool done = false;
            while (!done) {
                int m2 = lend;
                if (l != lend) {
                    for (int mm = l; mm >= lend + 1; --mm) {
                        float tst = e[mm - 2] * e[mm - 2];
                        if (tst <= (eps2 * fabsf(d[mm - 1])) * fabsf(d[mm - 2]) + safmin) { m2 = mm; break; }
                    }
                }
                if (m2 > lend) e[m2 - 2] = 0.0f;
                float p = d[l - 1];
                if (m2 == l) {
                    d[l - 1] = p;
                    l = l - 1;
                    if (l < lend) done = true;
                    continue;
                }
                if (m2 == l - 1) {
                    float rt1, rt2, c, s;
                    slaev2(d[l - 2], e[l - 2], d[l - 1], rt1, rt2, c, s);
                    for (int r = 0; r < 3; r++) {
                        float t = z[r][l - 1];
                        z[r][l - 1] = c * t - s * z[r][l - 2];
                        z[r][l - 2] = s * t + c * z[r][l - 2];
                    }
                    d[l - 2] = rt1; d[l - 1] = rt2; e[l - 2] = 0.0f;
                    l -= 2;
                    if (l < lend) done = true;
                    continue;
                }
                if (jtot == nmaxit) { done = true; continue; }
                jtot++;
                float g = (d[l - 2] - p) / (2.0f * e[l - 2]);
                float r = slapy2(g, 1.0f);
                g = d[m2 - 1] - p + (e[l - 2] / (g + s_sign(r, g)));
                float s = 1.0f, c = 1.0f;
                p = 0.0f;
                for (int i = m2; i <= l - 1; ++i) {
                    float f = s * e[i - 1];
                    float b = c * e[i - 1];
                    slartg_new(g, f, c, s, r);
                    if (i != m2) e[i - 2] = r;
                    g = d[i - 1] - p;
                    r = (d[i] - g) * s + 2.0f * c * b;
                    p = s * r;
                    d[i - 1] = g + p;
                    g = c * r - b;
                    cwork[i - 1] = c;
                    swork[i - 1] = s;
                }
                for (int j = m2; j <= l - 1; ++j) {
                    float ct = cwork[j - 1], st = swork[j - 1];
                    for (int r2 = 0; r2 < 3; r2++) {
                        float t = z[r2][j];
                        z[r2][j]     = ct * t - st * z[r2][j - 1];
                        z[r2][j - 1] = st * t + ct * z[r2][j - 1];
                    }
                }
                d[l - 1] -= p;
                e[l - 2] = g;
            }
        }
        if (jtot >= nmaxit) break;
    }
    // selection sort ascending + column swaps
    for (int ii = 2; ii <= n; ++ii) {
        int i = ii - 1, k = i;
        float p = d[i - 1];
        for (int j2 = ii; j2 <= n; ++j2) {
            if (d[j2 - 1] < p) { k = j2; p = d[j2 - 1]; }
        }
        if (k != i) {
            d[k - 1] = d[i - 1];
            d[i - 1] = p;
            for (int r2 = 0; r2 < 3; r2++) {
                float t = z[r2][i - 1];
                z[r2][i - 1] = z[r2][k - 1];
                z[r2][k - 1] = t;
            }
        }
    }
}

// ---------------------------------------------------------------------------
// Kernel A: per-(point, neighbor) MLP -> weights  (one thread per edge)
// GEMMs: OpenBLAS microkernel = sequential-k single-acc FMA (explicit fmaf).
// Layer 3: GEMM n=1 -> sgemv_t forward: 8 lane-accs stride-8 + vhaddps tree.
// Sigmoid: f32 op chain 1/(1+expf(-x)) with CR expf.
// ---------------------------------------------------------------------------
__global__ __launch_bounds__(256) void gnn_weights_kernel(
    const float* __restrict__ pos,
    const float* __restrict__ old_w,
    const float* __restrict__ normals,
    const int*   __restrict__ dense_l,
    const float* __restrict__ stddev,
    const float* __restrict__ W1, const float* __restrict__ b1,
    const float* __restrict__ W2, const float* __restrict__ b2,
    const float* __restrict__ W3, const float* __restrict__ b3,
    float* __restrict__ out_w)
{
    __shared__ __align__(16) float sW1[FINDIM * HID];
    __shared__ __align__(16) float sW2[2 * HID * HID];
    __shared__ float sb1[HID];
    __shared__ float sb2[HID];
    __shared__ float sW3[HID];

    int tid = threadIdx.x;
    for (int idx = tid; idx < FINDIM * HID; idx += 256) sW1[idx] = W1[idx];
    for (int idx = tid; idx < 2 * HID * HID; idx += 256) sW2[idx] = W2[idx];
    if (tid < HID) { sb1[tid] = b1[tid]; sb2[tid] = b2[tid]; sW3[tid] = W3[tid]; }
    __syncthreads();

    int t = blockIdx.x * 256 + tid;          // grid sized exactly N*K
    int i = t >> 4;
    int j = dense_l[t];
    float sd = stddev[0];

    float pix = pos[3 * i], piy = pos[3 * i + 1], piz = pos[3 * i + 2];
    float pjx = pos[3 * j], pjy = pos[3 * j + 1], pjz = pos[3 * j + 2];
    float dx = (pjx - pix) / sd, dy = (pjy - piy) / sd, dz = (pjz - piz) / sd;

    // np.linalg.norm: squares (no FMA), sequential sum, sqrt
    float dist;
    {
#pragma clang fp contract(off)
        float s0 = dx * dx;
        float s1 = s0 + dy * dy;
        float s2 = s1 + dz * dz;
        dist = sqrtf(s2);
    }

    float f[FINDIM];
    f[0] = dx; f[1] = dy; f[2] = dz; f[3] = dist;
    f[4] = normals[3 * i]; f[5] = normals[3 * i + 1]; f[6] = normals[3 * i + 2];
    f[7] = normals[3 * j]; f[8] = normals[3 * j + 1]; f[9] = normals[3 * j + 2];
    f[10] = old_w[t];

    // layer 1: (f @ W1) sequential-k FMA, then + b1, then relu
    float h[HID];
    #pragma unroll
    for (int q = 0; q < HID / 4; ++q) {
        float4 acc = make_float4(0.f, 0.f, 0.f, 0.f);
        #pragma unroll
        for (int ff = 0; ff < FINDIM; ++ff) {
            float4 wv = *reinterpret_cast<const float4*>(&sW1[ff * HID + 4 * q]);
            acc.x = fmaf(f[ff], wv.x, acc.x);
            acc.y = fmaf(f[ff], wv.y, acc.y);
            acc.z = fmaf(f[ff], wv.z, acc.z);
            acc.w = fmaf(f[ff], wv.w, acc.w);
        }
        float4 bb = *reinterpret_cast<const float4*>(&sb1[4 * q]);
        h[4 * q + 0] = fmaxf(acc.x + bb.x, 0.f);
        h[4 * q + 1] = fmaxf(acc.y + bb.y, 0.f);
        h[4 * q + 2] = fmaxf(acc.z + bb.z, 0.f);
        h[4 * q + 3] = fmaxf(acc.w + bb.w, 0.f);
    }

    // g = max over the 16 threads of this point
    float g[HID];
    #pragma unroll
    for (int hh = 0; hh < HID; ++hh) {
        float v = h[hh];
        v = fmaxf(v, __shfl_xor(v, 1));
        v = fmaxf(v, __shfl_xor(v, 2));
        v = fmaxf(v, __shfl_xor(v, 4));
        v = fmaxf(v, __shfl_xor(v, 8));
        g[hh] = v;
    }

    // layer 2: ([h,g] @ W2) sequential-k FMA (h rows 0..31, g rows 32..63),
    // then + b2, then relu
    float acc2[HID];
    #pragma unroll
    for (int hh = 0; hh < HID; ++hh) acc2[hh] = 0.f;
    #pragma unroll
    for (int ff = 0; ff < HID; ++ff) {
        float xf = h[ff];
        #pragma unroll
        for (int q = 0; q < HID / 4; ++q) {
            float4 wv = *reinterpret_cast<const float4*>(&sW2[ff * HID + 4 * q]);
            acc2[4 * q + 0] = fmaf(xf, wv.x, acc2[4 * q + 0]);
            acc2[4 * q + 1] = fmaf(xf, wv.y, acc2[4 * q + 1]);
            acc2[4 * q + 2] = fmaf(xf, wv.z, acc2[4 * q + 2]);
            acc2[4 * q + 3] = fmaf(xf, wv.w, acc2[4 * q + 3]);
        }
    }
    #pragma unroll
    for (int ff = 0; ff < HID; ++ff) {
        float xf = g[ff];
        #pragma unroll
        for (int q = 0; q < HID / 4; ++q) {
            float4 wv = *reinterpret_cast<const float4*>(&sW2[(HID + ff) * HID + 4 * q]);
            acc2[4 * q + 0] = fmaf(xf, wv.x, acc2[4 * q + 0]);
            acc2[4 * q + 1] = fmaf(xf, wv.y, acc2[4 * q + 1]);
            acc2[4 * q + 2] = fmaf(xf, wv.z, acc2[4 * q + 2]);
            acc2[4 * q + 3] = fmaf(xf, wv.w, acc2[4 * q + 3]);
        }
    }
    float h2[HID];
    #pragma unroll
    for (int hh = 0; hh < HID; ++hh) h2[hh] = fmaxf(acc2[hh] + sb2[hh], 0.f);

    // layer 3: sgemv_t (AVX2 microk): 8 lanes, stride-8 FMA chains of 4,
    // then tree ((l0+l4)+(l1+l5)) + ((l2+l6)+(l3+l7)); then + b3
    float lane[8];
    #pragma unroll
    for (int L = 0; L < 8; ++L) {
        float acc = h2[L] * sW3[L];
        acc = fmaf(h2[8 + L],  sW3[8 + L],  acc);
        acc = fmaf(h2[16 + L], sW3[16 + L], acc);
        acc = fmaf(h2[24 + L], sW3[24 + L], acc);
        lane[L] = acc;
    }
    float out;
    {
#pragma clang fp contract(off)
        float s0 = lane[0] + lane[4];
        float s1 = lane[1] + lane[5];
        float s2 = lane[2] + lane[6];
        float s3 = lane[3] + lane[7];
        out = (s0 + s1) + (s2 + s3);
        out = out + b3[0];
    }

    // sigmoid: f32 chain with CR expf (f64 exp -> round once)
    {
#pragma clang fp contract(off)
        float ef = (float)exp(-(double)out);
        out_w[t] = 1.0f / (1.0f + ef);
    }
}

// ---------------------------------------------------------------------------
// Kernel B: weighted covariance (+ threefry noise) + f32 LAPACK eigensolve
// ---------------------------------------------------------------------------
__global__ __launch_bounds__(256) void cov_eig_kernel(
    const float* __restrict__ pos,
    const int*   __restrict__ dense_l,
    const float* __restrict__ weights,
    float* __restrict__ out_normals)
{
#pragma clang fp contract(off)
    int i = blockIdx.x * 256 + threadIdx.x;
    if (i >= NPTS) return;

    float px[KNBR], py[KNBR], pz[KNBR], wk[KNBR];
    #pragma unroll
    for (int k = 0; k < KNBR; ++k) {
        int j = dense_l[i * KNBR + k];
        px[k] = pos[3 * j]; py[k] = pos[3 * j + 1]; pz[k] = pos[3 * j + 2];
        wk[k] = weights[i * KNBR + k];
    }

    // wsum: contiguous reduce n=16 -> numpy scalar-pairwise 8-acc tree
    float rw[8];
    #pragma unroll
    for (int j = 0; j < 8; ++j) rw[j] = wk[j] + wk[j + 8];
    float wsum = ((rw[0] + rw[1]) + (rw[2] + rw[3])) + ((rw[4] + rw[5]) + (rw[6] + rw[7]));

    // center numerator: strided reduce -> sequential-in-k elementwise adds
    float sx = 0.f, sy = 0.f, sz = 0.f;
    #pragma unroll
    for (int k = 0; k < KNBR; ++k) {
        float tx = px[k] * wk[k];
        float ty = py[k] * wk[k];
        float tz = pz[k] * wk[k];
        sx = sx + tx;
        sy = sy + ty;
        sz = sz + tz;
    }
    float cx = sx / wsum;
    float cy = sy / wsum;
    float cz = sz / wsum;

    // einsum SOP (baseline ISA, no FMA): sequential k, mul-then-add.
    // eigh(UPLO='L') lower triangle i>=j.
    float sxx = 0.f, syx = 0.f, szx = 0.f, syy = 0.f, szy = 0.f, szz = 0.f;
    #pragma unroll
    for (int k = 0; k < KNBR; ++k) {
        float dx = px[k] - cx, dy = py[k] - cy, dz = pz[k] - cz;
        float w = wk[k];
        float wx = dx * w, wy = dy * w, wz = dz * w;
        sxx += wx * dx;           // C[0][0]
        syx += wy * dx;           // C[1][0]
        szx += wz * dx;           // C[2][0]
        syy += wy * dy;           // C[1][1]
        szy += wz * dy;           // C[2][1]
        szz += wz * dz;           // C[2][2]
    }
    float a00 = sxx / wsum + NOISE0;
    float a10 = syx / wsum + NOISE0;
    float a20 = szx / wsum + NOISE0;
    float a11 = syy / wsum + NOISE1;
    float a21 = szy / wsum + NOISE1;
    float a22 = szz / wsum + NOISE2;

    // tridiagonalize (lower), then STEQR
    float d[3], e[2], tau, v2;
    ssytrd3(a00, a10, a20, a11, a21, a22, d, e, tau, v2);
    float z[3][3];
    ssteqr3(d, e, z);

    // stable argmin of |d|
    float ad0 = fabsf(d[0]), ad1 = fabsf(d[1]), ad2 = fabsf(d[2]);
    int c0 = 0;
    if (ad1 < ad0 && ad1 <= ad2) c0 = 1;
    else if (ad2 < ad0 && ad2 < ad1) c0 = 2;

    // SORMTR: Q*Z via SLARF (sgemv + sger, arch kernels -> FMA):
    //   w = fma(v2, z2, z1); tmp = (-tau)*w; z1 += tmp; z2 = fma(v2, tmp, z2)
    float z0 = z[0][c0], z1 = z[1][c0], z2 = z[2][c0];
    float wj  = fmaf(v2, z2, z1);
    float tmp = (-tau) * wj;
    float n0 = z0;
    float n1 = z1 + tmp;
    float n2 = fmaf(v2, tmp, z2);

    if (isnan(n0)) n0 = 0.f;
    if (isnan(n1)) n1 = 0.f;
    if (isnan(n2)) n2 = 0.f;
    out_normals[3 * i + 0] = n0;
    out_normals[3 * i + 1] = n1;
    out_normals[3 * i + 2] = n2;
}

// ---------------------------------------------------------------------------

extern "C" void kernel_launch(void* const* d_in, const int* in_sizes, int n_in,
                              void* d_out, int out_size, void* d_ws, size_t ws_size,
                              hipStream_t stream) {
    const float* pos      = (const float*)d_in[0];
    const float* old_w    = (const float*)d_in[1];
    // d_in[2] = batch (unused)
    const float* normals  = (const float*)d_in[3];
    // d_in[4] = edge_idx_l (unused)
    const int*   dense_l  = (const int*)d_in[5];
    const float* stddev   = (const float*)d_in[6];
    const float* W1 = (const float*)d_in[7];
    const float* b1 = (const float*)d_in[8];
    const float* W2 = (const float*)d_in[9];
    const float* b2 = (const float*)d_in[10];
    const float* W3 = (const float*)d_in[11];
    const float* b3 = (const float*)d_in[12];

    float* out_normals = (float*)d_out;                 // N*3
    float* out_weights = (float*)d_out + 3 * NPTS;      // N*K

    const int total_edges = NPTS * KNBR;                // 3,200,000 = 12500*256 exactly
    gnn_weights_kernel<<<total_edges / 256, 256, 0, stream>>>(
        pos, old_w, normals, dense_l, stddev, W1, b1, W2, b2, W3, b3, out_weights);

    cov_eig_kernel<<<(NPTS + 255) / 256, 256, 0, stream>>>(
        pos, dense_l, out_weights, out_normals);
}

// Round 10
// 404.684 us; speedup vs baseline: 1.1567x; 1.1567x over previous
//
#include <hip/hip_runtime.h>
#include <math.h>

#define NPTS 200000
#define KNBR 16
#define HID 32
#define FINDIM 11

// ---------------------------------------------------------------------------
// Compile-time Threefry-2x32 replication of jax.random.uniform(key(1),(100,3))
// flat elements 0,4,8 -> (u-0.5)*1e-8 noise added to cov columns.
// ---------------------------------------------------------------------------
constexpr unsigned tf_rotl(unsigned x, int r) { return (x << r) | (x >> (32 - r)); }

constexpr unsigned tf_first(unsigned c0, unsigned c1) {
    const unsigned k0 = 0u, k1 = 1u;
    const unsigned k2 = k0 ^ k1 ^ 0x1BD11BDAu;
    unsigned x0 = c0 + k0, x1 = c1 + k1;
    const int rA[4] = {13, 15, 26, 6};
    const int rB[4] = {17, 29, 16, 24};
    for (int i = 0; i < 4; ++i) { x0 += x1; x1 = tf_rotl(x1, rA[i]); x1 ^= x0; }
    x0 += k1; x1 += k2 + 1u;
    for (int i = 0; i < 4; ++i) { x0 += x1; x1 = tf_rotl(x1, rB[i]); x1 ^= x0; }
    x0 += k2; x1 += k0 + 2u;
    for (int i = 0; i < 4; ++i) { x0 += x1; x1 = tf_rotl(x1, rA[i]); x1 ^= x0; }
    x0 += k0; x1 += k1 + 3u;
    for (int i = 0; i < 4; ++i) { x0 += x1; x1 = tf_rotl(x1, rB[i]); x1 ^= x0; }
    x0 += k1; x1 += k2 + 4u;
    for (int i = 0; i < 4; ++i) { x0 += x1; x1 = tf_rotl(x1, rA[i]); x1 ^= x0; }
    x0 += k2; x1 += k0 + 5u;
    return x0;
}

constexpr float tf_noise(unsigned c0, unsigned c1) {
    unsigned bits = tf_first(c0, c1);
    unsigned fb = (bits >> 9) | 0x3f800000u;
    float u = __builtin_bit_cast(float, fb) - 1.0f;
    return (u - 0.5f) * 1e-8f;
}

constexpr float NOISE0 = tf_noise(0u, 150u);
constexpr float NOISE1 = tf_noise(4u, 154u);
constexpr float NOISE2 = tf_noise(8u, 158u);

// ---------------------------------------------------------------------------
// LAPACK-faithful 3x3 symmetric eigensolver, FLOAT32 (ssyevd path).
// LAPACK Fortran objects: baseline ISA (no FMA), contraction off.
// BLAS calls inside ssytd2/slarf: OpenBLAS arch kernels (FMA) -> fmaf.
// FP SEMANTICS FROZEN: verified bit-compatible with harness np reference (r8).
// ---------------------------------------------------------------------------

__device__ __forceinline__ float s_sign(float a, float b) {
    float aa = fabsf(a);
    return (b >= 0.0f) ? aa : -aa;
}

__device__ __forceinline__ float slapy2(float x, float y) {
#pragma clang fp contract(off)
    float xa = fabsf(x), ya = fabsf(y);
    float w = fmaxf(xa, ya), z = fminf(xa, ya);
    if (z == 0.0f) return w;
    float t = z / w;
    return w * sqrtf(1.0f + t * t);
}

__device__ __forceinline__ void slartg_new(float f, float g, float &c, float &s, float &r) {
#pragma clang fp contract(off)
    if (g == 0.0f) {
        c = 1.0f; s = 0.0f; r = f;
    } else if (f == 0.0f) {
        c = 0.0f; s = (g >= 0.0f) ? 1.0f : -1.0f; r = fabsf(g);
    } else {
        float d = sqrtf(f * f + g * g);
        c = fabsf(f) / d;
        r = (f >= 0.0f) ? d : -d;
        s = g / r;
    }
}

__device__ void slaev2(float a, float b, float c,
                       float &rt1, float &rt2, float &cs1, float &sn1) {
#pragma clang fp contract(off)
    float sm = a + c;
    float df = a - c;
    float adf = fabsf(df);
    float tb = b + b;
    float ab = fabsf(tb);
    float acmx, acmn;
    if (fabsf(a) > fabsf(c)) { acmx = a; acmn = c; } else { acmx = c; acmn = a; }
    float rt;
    if (adf > ab)      rt = adf * sqrtf(1.0f + (ab / adf) * (ab / adf));
    else if (adf < ab) rt = ab * sqrtf(1.0f + (adf / ab) * (adf / ab));
    else               rt = ab * sqrtf(2.0f);
    int sgn1;
    if (sm < 0.0f) {
        rt1 = 0.5f * (sm - rt);
        sgn1 = -1;
        rt2 = (acmx / rt1) * acmn - (b / rt1) * b;
    } else if (sm > 0.0f) {
        rt1 = 0.5f * (sm + rt);
        sgn1 = 1;
        rt2 = (acmx / rt1) * acmn - (b / rt1) * b;
    } else {
        rt1 = 0.5f * rt;
        rt2 = -0.5f * rt;
        sgn1 = 1;
    }
    int sgn2;
    float cs;
    if (df >= 0.0f) { cs = df + rt; sgn2 = 1; }
    else            { cs = df - rt; sgn2 = -1; }
    float acs = fabsf(cs);
    if (acs > ab) {
        float ct = -tb / cs;
        sn1 = 1.0f / sqrtf(1.0f + ct * ct);
        cs1 = ct * sn1;
    } else {
        if (ab == 0.0f) { cs1 = 1.0f; sn1 = 0.0f; }
        else {
            float tn = -cs / tb;
            cs1 = 1.0f / sqrtf(1.0f + tn * tn);
            sn1 = tn * cs1;
        }
    }
    if (sgn1 == sgn2) {
        float tn = cs1;
        cs1 = -sn1;
        sn1 = tn;
    }
}

__device__ void ssytrd3(float a00, float a10, float a20,
                        float a11, float a21, float a22,
                        float d[3], float e[2], float &tau, float &v2) {
#pragma clang fp contract(off)
    float alpha = a10;
    float xnorm = fabsf(a20);
    if (xnorm == 0.0f) {
        tau = 0.0f; v2 = 0.0f;
        d[0] = a00; d[1] = a11; d[2] = a22;
        e[0] = alpha; e[1] = a21;
        return;
    }
    float beta = -s_sign(slapy2(alpha, xnorm), alpha);
    tau = (beta - alpha) / beta;
    float sa = 1.0f / (alpha - beta);   // SSCAL: reciprocal then multiply
    v2 = a20 * sa;
    e[0] = beta;
    float x1 = fmaf(tau, a21 * v2, tau * a11);
    float x2 = fmaf(tau * v2, a22, tau * a21);
    float dot = fmaf(v2, x2, x1);
    float alphaw = (-0.5f * tau) * dot;
    float w1 = x1 + alphaw;
    float w2 = fmaf(alphaw, v2, x2);
    float b11 = (a11 - w1) - w1;
    float b21 = fmaf(v2, -w1, a21) - w2;
    float b22 = fmaf(w2, -v2, fmaf(v2, -w2, a22));
    d[0] = a00; d[1] = b11; d[2] = b22;
    e[1] = b21;
}

__device__ void ssteqr3(float d[3], float e[2], float z[3][3]) {
#pragma clang fp contract(off)
    const int n = 3;
    const float eps  = 0x1p-24f;
    const float eps2 = 0x1p-48f;
    const float safmin = 0x1p-126f;
    float cwork[2], swork[2];
    const int nmaxit = n * 30;
    int jtot = 0;
    int l1 = 1;

    for (int r = 0; r < 3; r++)
        for (int c = 0; c < 3; c++)
            z[r][c] = (r == c) ? 1.0f : 0.0f;

    while (true) {
        if (l1 > n) break;
        if (l1 > 1) e[l1 - 2] = 0.0f;
        int m = n;
        for (int mm = l1; mm <= n - 1; ++mm) {
            float tst = fabsf(e[mm - 1]);
            if (tst == 0.0f) { m = mm; break; }
            if (tst <= (sqrtf(fabsf(d[mm - 1])) * sqrtf(fabsf(d[mm]))) * eps) {
                e[mm - 1] = 0.0f; m = mm; break;
            }
        }
        int l = l1, lsv = l1, lend = m, lendsv = m;
        l1 = m + 1;
        if (lend == l) continue;

        if (fabsf(d[lend - 1]) < fabsf(d[l - 1])) { lend = lsv; l = lendsv; }

        if (lend > l) {
            // --- QL ---
            bool done = false;
            while (!done) {
                int m2 = lend;
                if (l != lend) {
                    for (int mm = l; mm <= lend - 1; ++mm) {
                        float tst = e[mm - 1] * e[mm - 1];
                        if (tst <= (eps2 * fabsf(d[mm - 1])) * fabsf(d[mm]) + safmin) { m2 = mm; break; }
                    }
                }
                if (m2 < lend) e[m2 - 1] = 0.0f;
                float p = d[l - 1];
                if (m2 == l) {
                    d[l - 1] = p;
                    l = l + 1;
                    if (l > lend) done = true;
                    continue;
                }
                if (m2 == l + 1) {
                    float rt1, rt2, c, s;
                    slaev2(d[l - 1], e[l - 1], d[l], rt1, rt2, c, s);
                    for (int r = 0; r < 3; r++) {
                        float t = z[r][l];
                        z[r][l]     = c * t - s * z[r][l - 1];
                        z[r][l - 1] = s * t + c * z[r][l - 1];
                    }
                    d[l - 1] = rt1; d[l] = rt2; e[l - 1] = 0.0f;
                    l += 2;
                    if (l > lend) done = true;
                    continue;
                }
                if (jtot == nmaxit) { done = true; continue; }
                jtot++;
                float g = (d[l] - p) / (2.0f * e[l - 1]);
                float r = slapy2(g, 1.0f);
                g = d[m2 - 1] - p + (e[l - 1] / (g + s_sign(r, g)));
                float s = 1.0f, c = 1.0f;
                p = 0.0f;
                for (int i = m2 - 1; i >= l; --i) {
                    float f = s * e[i - 1];
                    float b = c * e[i - 1];
                    slartg_new(g, f, c, s, r);
                    if (i != m2 - 1) e[i] = r;
                    g = d[i] - p;
                    r = (d[i - 1] - g) * s + 2.0f * c * b;
                    p = s * r;
                    d[i] = g + p;
                    g = c * r - b;
                    cwork[i - 1] = c;
                    swork[i - 1] = -s;
                }
                for (int j = m2 - 1; j >= l; --j) {
                    float ct = cwork[j - 1], st = swork[j - 1];
                    for (int r2 = 0; r2 < 3; r2++) {
                        float t = z[r2][j];
                        z[r2][j]     = ct * t - st * z[r2][j - 1];
                        z[r2][j - 1] = st * t + ct * z[r2][j - 1];
                    }
                }
                d[l - 1] -= p;
                e[l - 1] = g;
            }
        } else {
            // --- QR ---
            bool done = false;
            while (!done) {
                int m2 = lend;
                if (l != lend) {
                    for (int mm = l; mm >= lend + 1; --mm) {
                        float tst = e[mm - 2] * e[mm - 2];
                        if (tst <= (eps2 * fabsf(d[mm - 1])) * fabsf(d[mm - 2]) + safmin) { m2 = mm; break; }
                    }
                }
                if (m2 > lend) e[m2 - 2] = 0.0f;
                float p = d[l - 1];
                if (m2 == l) {
                    d[l - 1] = p;
                    l = l - 1;
                    if (l < lend) done = true;
                    continue;
                }
                if (m2 == l - 1) {
                    float rt1, rt2, c, s;
                    slaev2(d[l - 2], e[l - 2], d[l - 1], rt1, rt2, c, s);
                    for (int r = 0; r < 3; r++) {
                        float t = z[r][l - 1];
                        z[r][l - 1] = c * t - s * z[r][l - 2];
                        z[r][l - 2] = s * t + c * z[r][l - 2];
                    }
                    d[l - 2] = rt1; d[l - 1] = rt2; e[l - 2] = 0.0f;
                    l -= 2;
                    if (l < lend) done = true;
                    continue;
                }
                if (jtot == nmaxit) { done = true; continue; }
                jtot++;
                float g = (d[l - 2] - p) / (2.0f * e[l - 2]);
                float r = slapy2(g, 1.0f);
                g = d[m2 - 1] - p + (e[l - 2] / (g + s_sign(r, g)));
                float s = 1.0f, c = 1.0f;
                p = 0.0f;
                for (int i = m2; i <= l - 1; ++i) {
                    float f = s * e[i - 1];
                    float b = c * e[i - 1];
                    slartg_new(g, f, c, s, r);
                    if (i != m2) e[i - 2] = r;
                    g = d[i - 1] - p;
                    r = (d[i] - g) * s + 2.0f * c * b;
                    p = s * r;
                    d[i - 1] = g + p;
                    g = c * r - b;
                    cwork[i - 1] = c;
                    swork[i - 1] = s;
                }
                for (int j = m2; j <= l - 1; ++j) {
                    float ct = cwork[j - 1], st = swork[j - 1];
                    for (int r2 = 0; r2 < 3; r2++) {
                        float t = z[r2][j];
                        z[r2][j]     = ct * t - st * z[r2][j - 1];
                        z[r2][j - 1] = st * t + ct * z[r2][j - 1];
                    }
                }
                d[l - 1] -= p;
                e[l - 2] = g;
            }
        }
        if (jtot >= nmaxit) break;
    }
    // selection sort ascending + column swaps
    for (int ii = 2; ii <= n; ++ii) {
        int i = ii - 1, k = i;
        float p = d[i - 1];
        for (int j2 = ii; j2 <= n; ++j2) {
            if (d[j2 - 1] < p) { k = j2; p = d[j2 - 1]; }
        }
        if (k != i) {
            d[k - 1] = d[i - 1];
            d[i - 1] = p;
            for (int r2 = 0; r2 < 3; r2++) {
                float t = z[r2][i - 1];
                z[r2][i - 1] = z[r2][k - 1];
                z[r2][k - 1] = t;
            }
        }
    }
}

// ---------------------------------------------------------------------------
// Kernel A: per-(point, neighbor) MLP -> weights  (one thread per edge)
// r9 change: weights/biases read DIRECTLY from global with wave-uniform
// compile-time-constant offsets -> compiler emits s_load into SGPRs
// (scalar cache), used as the scalar operand of each v_fma.
// NO LDS staging, NO __syncthreads. FP chain identical to r8 (frozen).
// ---------------------------------------------------------------------------
__global__ __launch_bounds__(256) void gnn_weights_kernel(
    const float* __restrict__ pos,
    const float* __restrict__ old_w,
    const float* __restrict__ normals,
    const int*   __restrict__ dense_l,
    const float* __restrict__ stddev,
    const float* __restrict__ W1, const float* __restrict__ b1,
    const float* __restrict__ W2, const float* __restrict__ b2,
    const float* __restrict__ W3, const float* __restrict__ b3,
    float* __restrict__ out_w)
{
    int t = blockIdx.x * 256 + threadIdx.x;  // grid sized exactly N*K
    int i = t >> 4;
    int j = dense_l[t];
    float sd = stddev[0];

    float pix = pos[3 * i], piy = pos[3 * i + 1], piz = pos[3 * i + 2];
    float pjx = pos[3 * j], pjy = pos[3 * j + 1], pjz = pos[3 * j + 2];
    float dx = (pjx - pix) / sd, dy = (pjy - piy) / sd, dz = (pjz - piz) / sd;

    // np.linalg.norm: squares (no FMA), sequential sum, sqrt
    float dist;
    {
#pragma clang fp contract(off)
        float s0 = dx * dx;
        float s1 = s0 + dy * dy;
        float s2 = s1 + dz * dz;
        dist = sqrtf(s2);
    }

    float f[FINDIM];
    f[0] = dx; f[1] = dy; f[2] = dz; f[3] = dist;
    f[4] = normals[3 * i]; f[5] = normals[3 * i + 1]; f[6] = normals[3 * i + 2];
    f[7] = normals[3 * j]; f[8] = normals[3 * j + 1]; f[9] = normals[3 * j + 2];
    f[10] = old_w[t];

    // layer 1: (f @ W1) sequential-k FMA, then + b1, then relu
    float h[HID];
    #pragma unroll
    for (int n = 0; n < HID; ++n) {
        float acc = 0.f;
        #pragma unroll
        for (int ff = 0; ff < FINDIM; ++ff) {
            acc = fmaf(f[ff], W1[ff * HID + n], acc);
        }
        h[n] = fmaxf(acc + b1[n], 0.f);
    }

    // g = max over the 16 threads of this point (exact op: order-free)
    float g[HID];
    #pragma unroll
    for (int hh = 0; hh < HID; ++hh) {
        float v = h[hh];
        v = fmaxf(v, __shfl_xor(v, 1));
        v = fmaxf(v, __shfl_xor(v, 2));
        v = fmaxf(v, __shfl_xor(v, 4));
        v = fmaxf(v, __shfl_xor(v, 8));
        g[hh] = v;
    }

    // layer 2: ([h,g] @ W2) sequential-k FMA (h rows 0..31, g rows 32..63),
    // then + b2, then relu
    float acc2[HID];
    #pragma unroll
    for (int n = 0; n < HID; ++n) acc2[n] = 0.f;
    #pragma unroll
    for (int ff = 0; ff < HID; ++ff) {
        float xf = h[ff];
        #pragma unroll
        for (int n = 0; n < HID; ++n) {
            acc2[n] = fmaf(xf, W2[ff * HID + n], acc2[n]);
        }
    }
    #pragma unroll
    for (int ff = 0; ff < HID; ++ff) {
        float xf = g[ff];
        #pragma unroll
        for (int n = 0; n < HID; ++n) {
            acc2[n] = fmaf(xf, W2[(HID + ff) * HID + n], acc2[n]);
        }
    }
    float h2[HID];
    #pragma unroll
    for (int n = 0; n < HID; ++n) h2[n] = fmaxf(acc2[n] + b2[n], 0.f);

    // layer 3: sgemv_t microk: 8 lanes, stride-8 FMA chains of 4, hadd tree
    float lane[8];
    #pragma unroll
    for (int L = 0; L < 8; ++L) {
        float acc = h2[L] * W3[L];
        acc = fmaf(h2[8 + L],  W3[8 + L],  acc);
        acc = fmaf(h2[16 + L], W3[16 + L], acc);
        acc = fmaf(h2[24 + L], W3[24 + L], acc);
        lane[L] = acc;
    }
    float out;
    {
#pragma clang fp contract(off)
        float s0 = lane[0] + lane[4];
        float s1 = lane[1] + lane[5];
        float s2 = lane[2] + lane[6];
        float s3 = lane[3] + lane[7];
        out = (s0 + s1) + (s2 + s3);
        out = out + b3[0];
    }

    // sigmoid: f32 chain with CR expf (f64 exp -> round once)
    {
#pragma clang fp contract(off)
        float ef = (float)exp(-(double)out);
        out_w[t] = 1.0f / (1.0f + ef);
    }
}

// ---------------------------------------------------------------------------
// Kernel B: weighted covariance (+ threefry noise) + f32 LAPACK eigensolve
// (unchanged from r8 to isolate kernel A's delta)
// ---------------------------------------------------------------------------
__global__ __launch_bounds__(256) void cov_eig_kernel(
    const float* __restrict__ pos,
    const int*   __restrict__ dense_l,
    const float* __restrict__ weights,
    float* __restrict__ out_normals)
{
#pragma clang fp contract(off)
    int i = blockIdx.x * 256 + threadIdx.x;
    if (i >= NPTS) return;

    float px[KNBR], py[KNBR], pz[KNBR], wk[KNBR];
    #pragma unroll
    for (int k = 0; k < KNBR; ++k) {
        int j = dense_l[i * KNBR + k];
        px[k] = pos[3 * j]; py[k] = pos[3 * j + 1]; pz[k] = pos[3 * j + 2];
        wk[k] = weights[i * KNBR + k];
    }

    // wsum: contiguous reduce n=16 -> numpy scalar-pairwise 8-acc tree
    float rw[8];
    #pragma unroll
    for (int j = 0; j < 8; ++j) rw[j] = wk[j] + wk[j + 8];
    float wsum = ((rw[0] + rw[1]) + (rw[2] + rw[3])) + ((rw[4] + rw[5]) + (rw[6] + rw[7]));

    // center numerator: strided reduce -> sequential-in-k elementwise adds
    float sx = 0.f, sy = 0.f, sz = 0.f;
    #pragma unroll
    for (int k = 0; k < KNBR; ++k) {
        float tx = px[k] * wk[k];
        float ty = py[k] * wk[k];
        float tz = pz[k] * wk[k];
        sx = sx + tx;
        sy = sy + ty;
        sz = sz + tz;
    }
    float cx = sx / wsum;
    float cy = sy / wsum;
    float cz = sz / wsum;

    // einsum SOP (no FMA): sequential k, mul-then-add. Lower triangle i>=j.
    float sxx = 0.f, syx = 0.f, szx = 0.f, syy = 0.f, szy = 0.f, szz = 0.f;
    #pragma unroll
    for (int k = 0; k < KNBR; ++k) {
        float dx = px[k] - cx, dy = py[k] - cy, dz = pz[k] - cz;
        float w = wk[k];
        float wx = dx * w, wy = dy * w, wz = dz * w;
        sxx += wx * dx;
        syx += wy * dx;
        szx += wz * dx;
        syy += wy * dy;
        szy += wz * dy;
        szz += wz * dz;
    }
    float a00 = sxx / wsum + NOISE0;
    float a10 = syx / wsum + NOISE0;
    float a20 = szx / wsum + NOISE0;
    float a11 = syy / wsum + NOISE1;
    float a21 = szy / wsum + NOISE1;
    float a22 = szz / wsum + NOISE2;

    float d[3], e[2], tau, v2;
    ssytrd3(a00, a10, a20, a11, a21, a22, d, e, tau, v2);
    float z[3][3];
    ssteqr3(d, e, z);

    // stable argmin of |d|
    float ad0 = fabsf(d[0]), ad1 = fabsf(d[1]), ad2 = fabsf(d[2]);
    int c0 = 0;
    if (ad1 < ad0 && ad1 <= ad2) c0 = 1;
    else if (ad2 < ad0 && ad2 < ad1) c0 = 2;

    // SORMTR via SLARF (FMA)
    float z0 = z[0][c0], z1 = z[1][c0], z2 = z[2][c0];
    float wj  = fmaf(v2, z2, z1);
    float tmp = (-tau) * wj;
    float n0 = z0;
    float n1 = z1 + tmp;
    float n2 = fmaf(v2, tmp, z2);

    if (isnan(n0)) n0 = 0.f;
    if (isnan(n1)) n1 = 0.f;
    if (isnan(n2)) n2 = 0.f;
    out_normals[3 * i + 0] = n0;
    out_normals[3 * i + 1] = n1;
    out_normals[3 * i + 2] = n2;
}

// ---------------------------------------------------------------------------

extern "C" void kernel_launch(void* const* d_in, const int* in_sizes, int n_in,
                              void* d_out, int out_size, void* d_ws, size_t ws_size,
                              hipStream_t stream) {
    const float* pos      = (const float*)d_in[0];
    const float* old_w    = (const float*)d_in[1];
    // d_in[2] = batch (unused)
    const float* normals  = (const float*)d_in[3];
    // d_in[4] = edge_idx_l (unused)
    const int*   dense_l  = (const int*)d_in[5];
    const float* stddev   = (const float*)d_in[6];
    const float* W1 = (const float*)d_in[7];
    const float* b1 = (const float*)d_in[8];
    const float* W2 = (const float*)d_in[9];
    const float* b2 = (const float*)d_in[10];
    const float* W3 = (const float*)d_in[11];
    const float* b3 = (const float*)d_in[12];

    float* out_normals = (float*)d_out;                 // N*3
    float* out_weights = (float*)d_out + 3 * NPTS;      // N*K

    const int total_edges = NPTS * KNBR;                // 3,200,000 = 12500*256 exactly
    gnn_weights_kernel<<<total_edges / 256, 256, 0, stream>>>(
        pos, old_w, normals, dense_l, stddev, W1, b1, W2, b2, W3, b3, out_weights);

    cov_eig_kernel<<<(NPTS + 255) / 256, 256, 0, stream>>>(
        pos, dense_l, out_weights, out_normals);
}